// Round 4
// baseline (1613.793 us; speedup 1.0000x reference)
//
#include <hip/hip_runtime.h>
#include <hip/hip_fp16.h>

// ---------------------------------------------------------------------------
// 2-layer GCN. Round 4: fill_csr showed 8x write amplification (101MB HBM
// writes for a 12.8MB CSR) - random 8B stores through 8 non-coherent XCD L2s.
// Replace per-node CSR with a chunk x bucket counting-sort partition:
//   hist (LDS, no atomics) -> ordered scan (wave+block) -> scatter with LDS
//   cursors (each ~84B segment written by ONE workgroup -> ~1x write traffic).
// Aggregate: one workgroup per 128-node bucket, 32KB LDS fp32 accumulator,
// per edge: broadcast 8B entry + coalesced 128B fp16 gather + ds_add_f32.
// ---------------------------------------------------------------------------

#define D 64
#define NPB 128          // nodes per bucket (dst >> 7)
#define MAXB 784         // >= ceil(100000/128) = 782
#define CHUNK 8192       // edges per partition workgroup

// --- degree count: one int atomic per edge on dst (L2-resident, 400KB) -----
__global__ __launch_bounds__(256) void deg_kernel(const int* __restrict__ dst,
                                                  int* __restrict__ deg, int nE) {
    int e = blockIdx.x * 256 + threadIdx.x;
    if (e < nE) atomicAdd(&deg[dst[e]], 1);
}

// --- dinv = rsqrt(deg + 1) -------------------------------------------------
__global__ __launch_bounds__(256) void dinv_kernel(const int* __restrict__ deg,
                                                   float* __restrict__ dinv, int N) {
    int i = blockIdx.x * 256 + threadIdx.x;
    if (i < N) dinv[i] = rsqrtf((float)deg[i] + 1.0f);
}

// --- A1: per-chunk bucket histogram (LDS atomics only) ---------------------
__global__ __launch_bounds__(256) void hist_kernel(const int* __restrict__ dst,
                                                   int* __restrict__ counts,
                                                   int nE, int B) {
    __shared__ int hist[MAXB];
    int c = blockIdx.x;
    for (int b = threadIdx.x; b < B; b += 256) hist[b] = 0;
    __syncthreads();
    int e0 = c * CHUNK;
#pragma unroll
    for (int i = 0; i < CHUNK / 256; ++i) {
        int e = e0 + i * 256 + threadIdx.x;
        if (e < nE) atomicAdd(&hist[dst[e] >> 7], 1);
    }
    __syncthreads();
    for (int b = threadIdx.x; b < B; b += 256) counts[c * B + b] = hist[b];
}

// --- S1: per-bucket scan over chunks (one wave per bucket) -----------------
__global__ __launch_bounds__(256) void scan_chunks(const int* __restrict__ counts,
                                                   int* __restrict__ base,
                                                   int* __restrict__ bucketTotal,
                                                   int B, int C) {
    int b = blockIdx.x * 4 + (threadIdx.x >> 6);
    if (b >= B) return;
    int lane = threadIdx.x & 63;
    int running = 0;
    for (int c0 = 0; c0 < C; c0 += 64) {
        int c = c0 + lane;
        int v = (c < C) ? counts[c * B + b] : 0;
        int x = v;
#pragma unroll
        for (int s = 1; s < 64; s <<= 1) {
            int u = __shfl_up(x, s);
            if (lane >= s) x += u;
        }
        if (c < C) base[c * B + b] = running + x - v;   // exclusive within bucket
        running += __shfl(x, 63);
    }
    if (lane == 0) bucketTotal[b] = running;
}

// --- S2: block scan over bucket totals (B <= 1024) -------------------------
__global__ __launch_bounds__(1024) void scan_buckets(const int* __restrict__ bucketTotal,
                                                     int* __restrict__ bucketBase, int B) {
    __shared__ int sdata[1024];
    int t = threadIdx.x;
    int v = (t < B) ? bucketTotal[t] : 0;
    sdata[t] = v;
    __syncthreads();
    for (int s = 1; s < 1024; s <<= 1) {
        int u = (t >= s) ? sdata[t - s] : 0;
        __syncthreads();
        sdata[t] += u;
        __syncthreads();
    }
    if (t < B) bucketBase[t] = sdata[t] - v;       // exclusive
    if (t == B - 1) bucketBase[B] = sdata[t];      // total = nE
}

// --- S3: add bucket base into per-(chunk,bucket) offsets -------------------
__global__ __launch_bounds__(256) void add_bases(int* __restrict__ base,
                                                 const int* __restrict__ bucketBase,
                                                 int B) {
    int c = blockIdx.x;
    for (int b = threadIdx.x; b < B; b += 256) base[c * B + b] += bucketBase[b];
}

// --- A3: scatter entries via LDS cursors (no global atomics) ---------------
// Entry: {src | dloc<<17, norm(f32)}. Each (chunk,bucket) segment is written
// by exactly one workgroup -> near-1x HBM write traffic.
__global__ __launch_bounds__(256) void scatter_kernel(const int* __restrict__ src,
                                                      const int* __restrict__ dst,
                                                      const float* __restrict__ dinv,
                                                      const int* __restrict__ base,
                                                      int2* __restrict__ entries,
                                                      int nE, int B) {
    __shared__ int cur[MAXB];
    int c = blockIdx.x;
    for (int b = threadIdx.x; b < B; b += 256) cur[b] = base[c * B + b];
    __syncthreads();
    int e0 = c * CHUNK;
#pragma unroll
    for (int i = 0; i < CHUNK / 256; ++i) {
        int e = e0 + i * 256 + threadIdx.x;
        if (e < nE) {
            int s = src[e], d = dst[e];
            int b = d >> 7;
            int pos = atomicAdd(&cur[b], 1);
            float nrm = dinv[s] * dinv[d];
            entries[pos] = make_int2(s | ((d & (NPB - 1)) << 17), __float_as_int(nrm));
        }
    }
}

// --- Pass B: bucket aggregate. 1 workgroup = 128 nodes, 32KB LDS fp32 acc --
__global__ __launch_bounds__(256) void aggregate_b(const int2* __restrict__ entries,
                                                   const int* __restrict__ bucketBase,
                                                   const float* __restrict__ dinv,
                                                   const __half* __restrict__ H,
                                                   const float* __restrict__ bias,
                                                   float* __restrict__ out, int N) {
    __shared__ float acc[NPB * D];   // 32 KB
    int b = blockIdx.x;
    int t = threadIdx.x;
    int lane = t & 63;
    int w = t >> 6;
    for (int i = t; i < NPB * D; i += 256) acc[i] = 0.0f;
    __syncthreads();

    int s0 = bucketBase[b], s1 = bucketBase[b + 1];
    int len = s1 - s0;
    int per = (len + 3) >> 2;
    int ps = s0 + w * per;
    int pe = ps + per; if (pe > s1) pe = s1;

    int p = ps;
    for (; p + 4 <= pe; p += 4) {
        int2 e0 = entries[p], e1 = entries[p + 1], e2 = entries[p + 2], e3 = entries[p + 3];
        float h0 = __half2float(H[(size_t)(e0.x & 0x1FFFF) * D + lane]);
        float h1 = __half2float(H[(size_t)(e1.x & 0x1FFFF) * D + lane]);
        float h2 = __half2float(H[(size_t)(e2.x & 0x1FFFF) * D + lane]);
        float h3 = __half2float(H[(size_t)(e3.x & 0x1FFFF) * D + lane]);
        atomicAdd(&acc[((e0.x >> 17) & (NPB - 1)) * D + lane], h0 * __int_as_float(e0.y));
        atomicAdd(&acc[((e1.x >> 17) & (NPB - 1)) * D + lane], h1 * __int_as_float(e1.y));
        atomicAdd(&acc[((e2.x >> 17) & (NPB - 1)) * D + lane], h2 * __int_as_float(e2.y));
        atomicAdd(&acc[((e3.x >> 17) & (NPB - 1)) * D + lane], h3 * __int_as_float(e3.y));
    }
    for (; p < pe; ++p) {
        int2 e0 = entries[p];
        float h0 = __half2float(H[(size_t)(e0.x & 0x1FFFF) * D + lane]);
        atomicAdd(&acc[((e0.x >> 17) & (NPB - 1)) * D + lane], h0 * __int_as_float(e0.y));
    }
    __syncthreads();

    // epilogue: + bias + self-loop message; coalesced fp32 writes
    float bl = bias[lane];
    int nodeBase = b * NPB;
    for (int dl = w; dl < NPB; dl += 4) {
        int node = nodeBase + dl;
        if (node < N) {
            float di = dinv[node];
            float v = acc[dl * D + lane] + bl +
                      __half2float(H[(size_t)node * D + lane]) * (di * di);
            out[(size_t)node * D + lane] = v;
        }
    }
}

// --- H(fp16) = X(fp32) @ W^T : 64x64 block tile, 4x4 register tile ---------
__global__ __launch_bounds__(256) void gemm_xwt_h(const float* __restrict__ X,
                                                  const float* __restrict__ W,
                                                  __half* __restrict__ H, int N) {
    __shared__ float xt[64 * 68];
    __shared__ float wt[64 * 68];
    const int t = threadIdx.x;
    const int i0 = blockIdx.x * 64;
#pragma unroll
    for (int r = 0; r < 16; ++r) {
        int idx = r * 256 + t;
        int j = idx >> 6, k = idx & 63;
        wt[k * 68 + j] = W[idx];
    }
#pragma unroll
    for (int r = 0; r < 16; ++r) {
        int idx = r * 256 + t;
        int i = idx >> 6, k = idx & 63;
        float v = 0.0f;
        if (i0 + i < N) v = X[(size_t)(i0 + i) * D + k];
        xt[k * 68 + i] = v;
    }
    __syncthreads();
    const int tn = (t & 15) * 4;
    const int tc = (t >> 4) * 4;
    float acc[4][4] = {};
#pragma unroll 8
    for (int k = 0; k < 64; ++k) {
        const float4 xa = *(const float4*)(xt + k * 68 + tn);
        const float4 wb = *(const float4*)(wt + k * 68 + tc);
        acc[0][0] += xa.x * wb.x; acc[0][1] += xa.x * wb.y; acc[0][2] += xa.x * wb.z; acc[0][3] += xa.x * wb.w;
        acc[1][0] += xa.y * wb.x; acc[1][1] += xa.y * wb.y; acc[1][2] += xa.y * wb.z; acc[1][3] += xa.y * wb.w;
        acc[2][0] += xa.z * wb.x; acc[2][1] += xa.z * wb.y; acc[2][2] += xa.z * wb.z; acc[2][3] += xa.z * wb.w;
        acc[3][0] += xa.w * wb.x; acc[3][1] += xa.w * wb.y; acc[3][2] += xa.w * wb.z; acc[3][3] += xa.w * wb.w;
    }
#pragma unroll
    for (int a = 0; a < 4; ++a) {
        int i = i0 + tn + a;
        if (i < N) {
            union { __half2 h2[2]; uint2 u2; } pk;
            pk.h2[0].x = __float2half_rn(acc[a][0]);
            pk.h2[0].y = __float2half_rn(acc[a][1]);
            pk.h2[1].x = __float2half_rn(acc[a][2]);
            pk.h2[1].y = __float2half_rn(acc[a][3]);
            *(uint2*)(&H[(size_t)i * D + tc]) = pk.u2;
        }
    }
}

// --- fallback path (round-1 fp32 atomic) kernels ---------------------------
__global__ __launch_bounds__(256) void gemm_xwt(const float* __restrict__ X,
                                                const float* __restrict__ W,
                                                float* __restrict__ H, int N) {
    __shared__ float xt[64 * 68];
    __shared__ float wt[64 * 68];
    const int t = threadIdx.x;
    const int i0 = blockIdx.x * 64;
#pragma unroll
    for (int r = 0; r < 16; ++r) {
        int idx = r * 256 + t;
        int j = idx >> 6, k = idx & 63;
        wt[k * 68 + j] = W[idx];
    }
#pragma unroll
    for (int r = 0; r < 16; ++r) {
        int idx = r * 256 + t;
        int i = idx >> 6, k = idx & 63;
        float v = 0.0f;
        if (i0 + i < N) v = X[(size_t)(i0 + i) * D + k];
        xt[k * 68 + i] = v;
    }
    __syncthreads();
    const int tn = (t & 15) * 4;
    const int tc = (t >> 4) * 4;
    float acc[4][4] = {};
#pragma unroll 8
    for (int k = 0; k < 64; ++k) {
        const float4 xa = *(const float4*)(xt + k * 68 + tn);
        const float4 wb = *(const float4*)(wt + k * 68 + tc);
        acc[0][0] += xa.x * wb.x; acc[0][1] += xa.x * wb.y; acc[0][2] += xa.x * wb.z; acc[0][3] += xa.x * wb.w;
        acc[1][0] += xa.y * wb.x; acc[1][1] += xa.y * wb.y; acc[1][2] += xa.y * wb.z; acc[1][3] += xa.y * wb.w;
        acc[2][0] += xa.z * wb.x; acc[2][1] += xa.z * wb.y; acc[2][2] += xa.z * wb.z; acc[2][3] += xa.z * wb.w;
        acc[3][0] += xa.w * wb.x; acc[3][1] += xa.w * wb.y; acc[3][2] += xa.w * wb.z; acc[3][3] += xa.w * wb.w;
    }
#pragma unroll
    for (int a = 0; a < 4; ++a) {
        int i = i0 + tn + a;
        if (i < N) {
            float4 o = make_float4(acc[a][0], acc[a][1], acc[a][2], acc[a][3]);
            *(float4*)(H + (size_t)i * D + tc) = o;
        }
    }
}

__global__ __launch_bounds__(256) void init_out(const float* __restrict__ H,
                                                const float* __restrict__ dinv,
                                                const float* __restrict__ b,
                                                float* __restrict__ out, int N) {
    int idx4 = blockIdx.x * 256 + threadIdx.x;
    if (idx4 >= N * 16) return;
    int i = idx4 >> 4;
    int jc = idx4 & 15;
    float di = dinv[i];
    float s = di * di;
    float4 h4 = ((const float4*)H)[idx4];
    float4 b4 = ((const float4*)b)[jc];
    ((float4*)out)[idx4] = make_float4(b4.x + h4.x * s, b4.y + h4.y * s,
                                       b4.z + h4.z * s, b4.w + h4.w * s);
}

__global__ __launch_bounds__(256) void edge_scatter(const int* __restrict__ src,
                                                    const int* __restrict__ dst,
                                                    const float* __restrict__ dinv,
                                                    const float* __restrict__ H,
                                                    float* __restrict__ out, int nE) {
    int tid = blockIdx.x * 256 + threadIdx.x;
    int e = tid >> 4;
    if (e >= nE) return;
    int l = tid & 15;
    int s = src[e];
    int d = dst[e];
    float c = dinv[s] * dinv[d];
    float4 v = ((const float4*)H)[s * 16 + l];
    float* o = out + (size_t)d * D + l * 4;
    unsafeAtomicAdd(o + 0, v.x * c);
    unsafeAtomicAdd(o + 1, v.y * c);
    unsafeAtomicAdd(o + 2, v.z * c);
    unsafeAtomicAdd(o + 3, v.w * c);
}

static inline size_t align_up(size_t v, size_t a) { return (v + a - 1) & ~(a - 1); }

extern "C" void kernel_launch(void* const* d_in, const int* in_sizes, int n_in,
                              void* d_out, int out_size, void* d_ws, size_t ws_size,
                              hipStream_t stream) {
    const float* x  = (const float*)d_in[0];
    const int*   ei = (const int*)d_in[1];
    const float* W1 = (const float*)d_in[2];
    const float* b1 = (const float*)d_in[3];
    const float* W2 = (const float*)d_in[4];
    const float* b2 = (const float*)d_in[5];
    float* out = (float*)d_out;

    const int N  = in_sizes[0] / D;   // 100000
    const int nE = in_sizes[1] / 2;   // 1600000
    const int* src = ei;
    const int* dstv = ei + nE;

    const int B = (N + NPB - 1) / NPB;      // 782 (<= MAXB, <= 1024 for S2)
    const int C = (nE + CHUNK - 1) / CHUNK; // 196

    // --- workspace layout (bump allocator, 256B aligned) ---
    char* base_p = (char*)d_ws;
    size_t o = 0;
    int* deg    = (int*)(base_p + o);  o = align_up(o + (size_t)N * 4, 256);
    size_t zero_end = o;               // memset deg only
    float* dinv = (float*)(base_p + o); o = align_up(o + (size_t)N * 4, 256);
    int* counts = (int*)(base_p + o);  o = align_up(o + (size_t)C * B * 4, 256);
    int* cbase  = (int*)(base_p + o);  o = align_up(o + (size_t)C * B * 4, 256);
    int* btot   = (int*)(base_p + o);  o = align_up(o + (size_t)B * 4, 256);
    int* bbase  = (int*)(base_p + o);  o = align_up(o + (size_t)(B + 1) * 4, 256);
    int2* entries = (int2*)(base_p + o); o = align_up(o + (size_t)nE * 8, 256);
    __half* Hh  = (__half*)(base_p + o); o = align_up(o + (size_t)N * D * 2, 256);
    size_t need = o;                   // ~27.6 MB

    int gb_e = (nE + 255) / 256;
    int gb_n = (N + 255) / 256;
    int gb_g = (N + 63) / 64;

    if (ws_size >= need && B <= 1024 && B <= MAXB) {
        hipMemsetAsync(base_p, 0, zero_end, stream);
        deg_kernel<<<gb_e, 256, 0, stream>>>(dstv, deg, nE);
        dinv_kernel<<<gb_n, 256, 0, stream>>>(deg, dinv, N);
        // partition build (once, reused both layers)
        hist_kernel<<<C, 256, 0, stream>>>(dstv, counts, nE, B);
        scan_chunks<<<(B + 3) / 4, 256, 0, stream>>>(counts, cbase, btot, B, C);
        scan_buckets<<<1, 1024, 0, stream>>>(btot, bbase, B);
        add_bases<<<C, 256, 0, stream>>>(cbase, bbase, B);
        scatter_kernel<<<C, 256, 0, stream>>>(src, dstv, dinv, cbase, entries, nE, B);
        // layer 1
        gemm_xwt_h<<<gb_g, 256, 0, stream>>>(x, W1, Hh, N);
        aggregate_b<<<B, 256, 0, stream>>>(entries, bbase, dinv, Hh, b1, out, N);
        // layer 2 (agg1 lives in d_out, fp32)
        gemm_xwt_h<<<gb_g, 256, 0, stream>>>(out, W2, Hh, N);
        aggregate_b<<<B, 256, 0, stream>>>(entries, bbase, dinv, Hh, b2, out, N);
    } else {
        // ---------------- fallback: round-1 atomic path ----------------
        float* bufA = (float*)(base_p + align_up((size_t)N * 4 * 2, 256));
        hipMemsetAsync(base_p, 0, zero_end, stream);
        deg_kernel<<<gb_e, 256, 0, stream>>>(dstv, deg, nE);
        dinv_kernel<<<gb_n, 256, 0, stream>>>(deg, dinv, N);
        int gb_i = (N * 16 + 255) / 256;
        int gb_e16 = (int)(((long long)nE * 16 + 255) / 256);
        gemm_xwt<<<gb_g, 256, 0, stream>>>(x, W1, bufA, N);
        init_out<<<gb_i, 256, 0, stream>>>(bufA, dinv, b1, out, N);
        edge_scatter<<<gb_e16, 256, 0, stream>>>(src, dstv, dinv, bufA, out, nE);
        gemm_xwt<<<gb_g, 256, 0, stream>>>(out, W2, bufA, N);
        init_out<<<gb_i, 256, 0, stream>>>(bufA, dinv, b2, out, N);
        edge_scatter<<<gb_e16, 256, 0, stream>>>(src, dstv, dinv, bufA, out, nE);
    }
}

// Round 5
// 305.210 us; speedup vs baseline: 5.2875x; 5.2875x over previous
//
#include <hip/hip_runtime.h>
#include <hip/hip_fp16.h>

// ---------------------------------------------------------------------------
// 2-layer GCN. Round 5: round-4's bucket aggregate starved parallelism
// (782 blocks, 2% HBM, 694us). Revert aggregate to round-3's per-node wave
// form (25000 blocks, proven 100us) but feed it a node-sorted CSR built via
// the round-4 partition (which DID fix fill_csr's 8x write amplification):
//   hist -> scans -> scatter0 (4B entries, LDS cursors, chunk x bucket)
//   -> regroup_count (per-bucket node counts -> off/deg/dinv, no global
//      atomics) -> regroup_scatter (node-sorted {src,norm}, writes stay in
//      one 16KB L2-resident window per bucket).
// deg_kernel / dinv_kernel / alloc_offsets / fill_csr all eliminated.
// H(fp16) aliases the dead entries0 buffer; ws ~28 MB.
// ---------------------------------------------------------------------------

#define D 64
#define NPB 128          // nodes per bucket (dst >> 7)
#define MAXB 784         // >= ceil(100000/128) = 782
#define CHUNK 8192       // edges per partition chunk

// --- A1: per-chunk bucket histogram (LDS atomics only) ---------------------
__global__ __launch_bounds__(256) void hist_kernel(const int* __restrict__ dst,
                                                   int* __restrict__ counts,
                                                   int nE, int B) {
    __shared__ int hist[MAXB];
    int c = blockIdx.x;
    for (int b = threadIdx.x; b < B; b += 256) hist[b] = 0;
    __syncthreads();
    int e0 = c * CHUNK;
#pragma unroll
    for (int i = 0; i < CHUNK / 256; ++i) {
        int e = e0 + i * 256 + threadIdx.x;
        if (e < nE) atomicAdd(&hist[dst[e] >> 7], 1);
    }
    __syncthreads();
    for (int b = threadIdx.x; b < B; b += 256) counts[c * B + b] = hist[b];
}

// --- S1: per-bucket scan over chunks (one wave per bucket) -----------------
__global__ __launch_bounds__(256) void scan_chunks(const int* __restrict__ counts,
                                                   int* __restrict__ base,
                                                   int* __restrict__ bucketTotal,
                                                   int B, int C) {
    int b = blockIdx.x * 4 + (threadIdx.x >> 6);
    if (b >= B) return;
    int lane = threadIdx.x & 63;
    int running = 0;
    for (int c0 = 0; c0 < C; c0 += 64) {
        int c = c0 + lane;
        int v = (c < C) ? counts[c * B + b] : 0;
        int x = v;
#pragma unroll
        for (int s = 1; s < 64; s <<= 1) {
            int u = __shfl_up(x, s);
            if (lane >= s) x += u;
        }
        if (c < C) base[c * B + b] = running + x - v;   // exclusive within bucket
        running += __shfl(x, 63);
    }
    if (lane == 0) bucketTotal[b] = running;
}

// --- S2: block scan over bucket totals (B <= 1024) -------------------------
__global__ __launch_bounds__(1024) void scan_buckets(const int* __restrict__ bucketTotal,
                                                     int* __restrict__ bucketBase, int B) {
    __shared__ int sdata[1024];
    int t = threadIdx.x;
    int v = (t < B) ? bucketTotal[t] : 0;
    sdata[t] = v;
    __syncthreads();
    for (int s = 1; s < 1024; s <<= 1) {
        int u = (t >= s) ? sdata[t - s] : 0;
        __syncthreads();
        sdata[t] += u;
        __syncthreads();
    }
    if (t < B) bucketBase[t] = sdata[t] - v;       // exclusive
    if (t == B - 1) bucketBase[B] = sdata[t];      // total = nE
}

// --- S3: add bucket base into per-(chunk,bucket) offsets -------------------
__global__ __launch_bounds__(256) void add_bases(int* __restrict__ base,
                                                 const int* __restrict__ bucketBase,
                                                 int B) {
    int c = blockIdx.x;
    for (int b = threadIdx.x; b < B; b += 256) base[c * B + b] += bucketBase[b];
}

// --- A3: scatter 4B entries (src | dloc<<17) via LDS cursors ---------------
// Each (chunk,bucket) segment is written by exactly one workgroup.
__global__ __launch_bounds__(256) void scatter0_kernel(const int* __restrict__ src,
                                                       const int* __restrict__ dst,
                                                       const int* __restrict__ base,
                                                       int* __restrict__ entries0,
                                                       int nE, int B) {
    __shared__ int cur[MAXB];
    int c = blockIdx.x;
    for (int b = threadIdx.x; b < B; b += 256) cur[b] = base[c * B + b];
    __syncthreads();
    int e0 = c * CHUNK;
#pragma unroll
    for (int i = 0; i < CHUNK / 256; ++i) {
        int e = e0 + i * 256 + threadIdx.x;
        if (e < nE) {
            int s = src[e], d = dst[e];
            int pos = atomicAdd(&cur[d >> 7], 1);
            entries0[pos] = s | ((d & (NPB - 1)) << 17);
        }
    }
}

// --- A4: per-bucket node counts -> off / deg / dinv (no global atomics) ----
__global__ __launch_bounds__(256) void regroup_count(const int* __restrict__ entries0,
                                                     const int* __restrict__ bbase,
                                                     int* __restrict__ off,
                                                     int* __restrict__ deg,
                                                     float* __restrict__ dinv, int N) {
    __shared__ int cnt[NPB];
    __shared__ int scn[NPB];
    int b = blockIdx.x;
    int t = threadIdx.x;
    if (t < NPB) cnt[t] = 0;
    __syncthreads();
    int s0 = bbase[b], s1 = bbase[b + 1];
    for (int p = s0 + t; p < s1; p += 256)
        atomicAdd(&cnt[(entries0[p] >> 17) & (NPB - 1)], 1);
    __syncthreads();
    if (t < NPB) scn[t] = cnt[t];
    __syncthreads();
    for (int s = 1; s < NPB; s <<= 1) {
        int u = 0;
        if (t < NPB && t >= s) u = scn[t - s];
        __syncthreads();
        if (t < NPB) scn[t] += u;
        __syncthreads();
    }
    if (t < NPB) {
        int node = b * NPB + t;
        if (node < N) {
            int c = cnt[t];
            off[node]  = s0 + scn[t] - c;     // exclusive prefix
            deg[node]  = c;
            dinv[node] = rsqrtf((float)c + 1.0f);
        }
    }
}

// --- A5: node-sorted {src, norm} entries; writes within 16KB/bucket --------
__global__ __launch_bounds__(256) void regroup_scatter(const int* __restrict__ entries0,
                                                       const int* __restrict__ bbase,
                                                       const int* __restrict__ off,
                                                       const float* __restrict__ dinv,
                                                       int2* __restrict__ entries1, int N) {
    __shared__ int cur[NPB];
    int b = blockIdx.x;
    int t = threadIdx.x;
    if (t < NPB) {
        int node = b * NPB + t;
        cur[t] = (node < N) ? off[node] : 0;
    }
    __syncthreads();
    int s0 = bbase[b], s1 = bbase[b + 1];
    for (int p = s0 + t; p < s1; p += 256) {
        int e = entries0[p];
        int s = e & 0x1FFFF;
        int dloc = (e >> 17) & (NPB - 1);
        int pos = atomicAdd(&cur[dloc], 1);
        float nrm = dinv[s] * dinv[b * NPB + dloc];
        entries1[pos] = make_int2(s, __float_as_int(nrm));
    }
}

// --- aggregate: one wave per node, lane = column, fp16 H, unroll-8 ---------
__global__ __launch_bounds__(256) void aggregate(const int2* __restrict__ csr,
                                                 const int* __restrict__ off,
                                                 const int* __restrict__ deg,
                                                 const float* __restrict__ dinv,
                                                 const __half* __restrict__ H,
                                                 const float* __restrict__ b,
                                                 float* __restrict__ out, int N) {
    int node = blockIdx.x * 4 + (threadIdx.x >> 6);
    if (node >= N) return;
    int lane = threadIdx.x & 63;
    int beg = off[node];
    int end = beg + deg[node];
    float dd = dinv[node];
    float acc = b[lane] + __half2float(H[(size_t)node * D + lane]) * (dd * dd);
    int p = beg;
    for (; p + 8 <= end; p += 8) {
        int2 e0 = csr[p],     e1 = csr[p + 1], e2 = csr[p + 2], e3 = csr[p + 3];
        int2 e4 = csr[p + 4], e5 = csr[p + 5], e6 = csr[p + 6], e7 = csr[p + 7];
        float h0 = __half2float(H[(size_t)e0.x * D + lane]);
        float h1 = __half2float(H[(size_t)e1.x * D + lane]);
        float h2 = __half2float(H[(size_t)e2.x * D + lane]);
        float h3 = __half2float(H[(size_t)e3.x * D + lane]);
        float h4 = __half2float(H[(size_t)e4.x * D + lane]);
        float h5 = __half2float(H[(size_t)e5.x * D + lane]);
        float h6 = __half2float(H[(size_t)e6.x * D + lane]);
        float h7 = __half2float(H[(size_t)e7.x * D + lane]);
        acc += h0 * __int_as_float(e0.y);
        acc += h1 * __int_as_float(e1.y);
        acc += h2 * __int_as_float(e2.y);
        acc += h3 * __int_as_float(e3.y);
        acc += h4 * __int_as_float(e4.y);
        acc += h5 * __int_as_float(e5.y);
        acc += h6 * __int_as_float(e6.y);
        acc += h7 * __int_as_float(e7.y);
    }
    for (; p + 4 <= end; p += 4) {
        int2 e0 = csr[p], e1 = csr[p + 1], e2 = csr[p + 2], e3 = csr[p + 3];
        float h0 = __half2float(H[(size_t)e0.x * D + lane]);
        float h1 = __half2float(H[(size_t)e1.x * D + lane]);
        float h2 = __half2float(H[(size_t)e2.x * D + lane]);
        float h3 = __half2float(H[(size_t)e3.x * D + lane]);
        acc += h0 * __int_as_float(e0.y);
        acc += h1 * __int_as_float(e1.y);
        acc += h2 * __int_as_float(e2.y);
        acc += h3 * __int_as_float(e3.y);
    }
    for (; p < end; ++p) {
        int2 e0 = csr[p];
        acc += __half2float(H[(size_t)e0.x * D + lane]) * __int_as_float(e0.y);
    }
    out[(size_t)node * D + lane] = acc;
}

// --- H(fp16) = X(fp32) @ W^T : 64x64 block tile, 4x4 register tile ---------
__global__ __launch_bounds__(256) void gemm_xwt_h(const float* __restrict__ X,
                                                  const float* __restrict__ W,
                                                  __half* __restrict__ H, int N) {
    __shared__ float xt[64 * 68];
    __shared__ float wt[64 * 68];
    const int t = threadIdx.x;
    const int i0 = blockIdx.x * 64;
#pragma unroll
    for (int r = 0; r < 16; ++r) {
        int idx = r * 256 + t;
        int j = idx >> 6, k = idx & 63;
        wt[k * 68 + j] = W[idx];
    }
#pragma unroll
    for (int r = 0; r < 16; ++r) {
        int idx = r * 256 + t;
        int i = idx >> 6, k = idx & 63;
        float v = 0.0f;
        if (i0 + i < N) v = X[(size_t)(i0 + i) * D + k];
        xt[k * 68 + i] = v;
    }
    __syncthreads();
    const int tn = (t & 15) * 4;
    const int tc = (t >> 4) * 4;
    float acc[4][4] = {};
#pragma unroll 8
    for (int k = 0; k < 64; ++k) {
        const float4 xa = *(const float4*)(xt + k * 68 + tn);
        const float4 wb = *(const float4*)(wt + k * 68 + tc);
        acc[0][0] += xa.x * wb.x; acc[0][1] += xa.x * wb.y; acc[0][2] += xa.x * wb.z; acc[0][3] += xa.x * wb.w;
        acc[1][0] += xa.y * wb.x; acc[1][1] += xa.y * wb.y; acc[1][2] += xa.y * wb.z; acc[1][3] += xa.y * wb.w;
        acc[2][0] += xa.z * wb.x; acc[2][1] += xa.z * wb.y; acc[2][2] += xa.z * wb.z; acc[2][3] += xa.z * wb.w;
        acc[3][0] += xa.w * wb.x; acc[3][1] += xa.w * wb.y; acc[3][2] += xa.w * wb.z; acc[3][3] += xa.w * wb.w;
    }
#pragma unroll
    for (int a = 0; a < 4; ++a) {
        int i = i0 + tn + a;
        if (i < N) {
            union { __half2 h2[2]; uint2 u2; } pk;
            pk.h2[0].x = __float2half_rn(acc[a][0]);
            pk.h2[0].y = __float2half_rn(acc[a][1]);
            pk.h2[1].x = __float2half_rn(acc[a][2]);
            pk.h2[1].y = __float2half_rn(acc[a][3]);
            *(uint2*)(&H[(size_t)i * D + tc]) = pk.u2;
        }
    }
}

// --- fallback path (round-1 fp32 atomic) kernels ---------------------------
__global__ __launch_bounds__(256) void deg_kernel(const int* __restrict__ dst,
                                                  int* __restrict__ deg, int nE) {
    int e = blockIdx.x * 256 + threadIdx.x;
    if (e < nE) atomicAdd(&deg[dst[e]], 1);
}

__global__ __launch_bounds__(256) void dinv_kernel(const int* __restrict__ deg,
                                                   float* __restrict__ dinv, int N) {
    int i = blockIdx.x * 256 + threadIdx.x;
    if (i < N) dinv[i] = rsqrtf((float)deg[i] + 1.0f);
}

__global__ __launch_bounds__(256) void gemm_xwt(const float* __restrict__ X,
                                                const float* __restrict__ W,
                                                float* __restrict__ H, int N) {
    __shared__ float xt[64 * 68];
    __shared__ float wt[64 * 68];
    const int t = threadIdx.x;
    const int i0 = blockIdx.x * 64;
#pragma unroll
    for (int r = 0; r < 16; ++r) {
        int idx = r * 256 + t;
        int j = idx >> 6, k = idx & 63;
        wt[k * 68 + j] = W[idx];
    }
#pragma unroll
    for (int r = 0; r < 16; ++r) {
        int idx = r * 256 + t;
        int i = idx >> 6, k = idx & 63;
        float v = 0.0f;
        if (i0 + i < N) v = X[(size_t)(i0 + i) * D + k];
        xt[k * 68 + i] = v;
    }
    __syncthreads();
    const int tn = (t & 15) * 4;
    const int tc = (t >> 4) * 4;
    float acc[4][4] = {};
#pragma unroll 8
    for (int k = 0; k < 64; ++k) {
        const float4 xa = *(const float4*)(xt + k * 68 + tn);
        const float4 wb = *(const float4*)(wt + k * 68 + tc);
        acc[0][0] += xa.x * wb.x; acc[0][1] += xa.x * wb.y; acc[0][2] += xa.x * wb.z; acc[0][3] += xa.x * wb.w;
        acc[1][0] += xa.y * wb.x; acc[1][1] += xa.y * wb.y; acc[1][2] += xa.y * wb.z; acc[1][3] += xa.y * wb.w;
        acc[2][0] += xa.z * wb.x; acc[2][1] += xa.z * wb.y; acc[2][2] += xa.z * wb.z; acc[2][3] += xa.z * wb.w;
        acc[3][0] += xa.w * wb.x; acc[3][1] += xa.w * wb.y; acc[3][2] += xa.w * wb.z; acc[3][3] += xa.w * wb.w;
    }
#pragma unroll
    for (int a = 0; a < 4; ++a) {
        int i = i0 + tn + a;
        if (i < N) {
            float4 o = make_float4(acc[a][0], acc[a][1], acc[a][2], acc[a][3]);
            *(float4*)(H + (size_t)i * D + tc) = o;
        }
    }
}

__global__ __launch_bounds__(256) void init_out(const float* __restrict__ H,
                                                const float* __restrict__ dinv,
                                                const float* __restrict__ b,
                                                float* __restrict__ out, int N) {
    int idx4 = blockIdx.x * 256 + threadIdx.x;
    if (idx4 >= N * 16) return;
    int i = idx4 >> 4;
    int jc = idx4 & 15;
    float di = dinv[i];
    float s = di * di;
    float4 h4 = ((const float4*)H)[idx4];
    float4 b4 = ((const float4*)b)[jc];
    ((float4*)out)[idx4] = make_float4(b4.x + h4.x * s, b4.y + h4.y * s,
                                       b4.z + h4.z * s, b4.w + h4.w * s);
}

__global__ __launch_bounds__(256) void edge_scatter(const int* __restrict__ src,
                                                    const int* __restrict__ dst,
                                                    const float* __restrict__ dinv,
                                                    const float* __restrict__ H,
                                                    float* __restrict__ out, int nE) {
    int tid = blockIdx.x * 256 + threadIdx.x;
    int e = tid >> 4;
    if (e >= nE) return;
    int l = tid & 15;
    int s = src[e];
    int d = dst[e];
    float c = dinv[s] * dinv[d];
    float4 v = ((const float4*)H)[s * 16 + l];
    float* o = out + (size_t)d * D + l * 4;
    unsafeAtomicAdd(o + 0, v.x * c);
    unsafeAtomicAdd(o + 1, v.y * c);
    unsafeAtomicAdd(o + 2, v.z * c);
    unsafeAtomicAdd(o + 3, v.w * c);
}

static inline size_t align_up(size_t v, size_t a) { return (v + a - 1) & ~(a - 1); }

extern "C" void kernel_launch(void* const* d_in, const int* in_sizes, int n_in,
                              void* d_out, int out_size, void* d_ws, size_t ws_size,
                              hipStream_t stream) {
    const float* x  = (const float*)d_in[0];
    const int*   ei = (const int*)d_in[1];
    const float* W1 = (const float*)d_in[2];
    const float* b1 = (const float*)d_in[3];
    const float* W2 = (const float*)d_in[4];
    const float* b2 = (const float*)d_in[5];
    float* out = (float*)d_out;

    const int N  = in_sizes[0] / D;   // 100000
    const int nE = in_sizes[1] / 2;   // 1600000
    const int* src = ei;
    const int* dstv = ei + nE;

    const int B = (N + NPB - 1) / NPB;      // 782
    const int C = (nE + CHUNK - 1) / CHUNK; // 196

    // --- workspace layout (bump allocator, 256B aligned) ---
    char* base_p = (char*)d_ws;
    size_t o = 0;
    int* counts = (int*)(base_p + o);  o = align_up(o + (size_t)C * B * 4, 256);
    int* cbase  = (int*)(base_p + o);  o = align_up(o + (size_t)C * B * 4, 256);
    int* btot   = (int*)(base_p + o);  o = align_up(o + (size_t)B * 4, 256);
    int* bbase  = (int*)(base_p + o);  o = align_up(o + (size_t)(B + 1) * 4, 256);
    int* off    = (int*)(base_p + o);  o = align_up(o + (size_t)N * 4, 256);
    int* deg    = (int*)(base_p + o);  o = align_up(o + (size_t)N * 4, 256);
    float* dinv = (float*)(base_p + o); o = align_up(o + (size_t)N * 4, 256);
    int2* entries1 = (int2*)(base_p + o); o = align_up(o + (size_t)nE * 8, 256);
    // region2: entries0 (nE*4) while building; Hh (N*D*2) afterwards (aliased)
    size_t r2 = (size_t)nE * 4 > (size_t)N * D * 2 ? (size_t)nE * 4 : (size_t)N * D * 2;
    int* entries0 = (int*)(base_p + o);
    __half* Hh    = (__half*)(base_p + o);
    o = align_up(o + r2, 256);
    size_t need = o;   // ~28 MB

    int gb_n = (N + 255) / 256;
    int gb_g = (N + 63) / 64;
    int gb_e = (nE + 255) / 256;

    if (ws_size >= need && B <= MAXB && B <= 1024) {
        // ---- partition build (once, reused both layers) ----
        hist_kernel<<<C, 256, 0, stream>>>(dstv, counts, nE, B);
        scan_chunks<<<(B + 3) / 4, 256, 0, stream>>>(counts, cbase, btot, B, C);
        scan_buckets<<<1, 1024, 0, stream>>>(btot, bbase, B);
        add_bases<<<C, 256, 0, stream>>>(cbase, bbase, B);
        scatter0_kernel<<<C, 256, 0, stream>>>(src, dstv, cbase, entries0, nE, B);
        regroup_count<<<B, 256, 0, stream>>>(entries0, bbase, off, deg, dinv, N);
        regroup_scatter<<<B, 256, 0, stream>>>(entries0, bbase, off, dinv, entries1, N);
        // (entries0 dead from here; its memory becomes Hh)

        int gb_a = (N + 3) / 4;
        // layer 1
        gemm_xwt_h<<<gb_g, 256, 0, stream>>>(x, W1, Hh, N);
        aggregate<<<gb_a, 256, 0, stream>>>(entries1, off, deg, dinv, Hh, b1, out, N);
        // layer 2 (agg1 lives in d_out, fp32)
        gemm_xwt_h<<<gb_g, 256, 0, stream>>>(out, W2, Hh, N);
        aggregate<<<gb_a, 256, 0, stream>>>(entries1, off, deg, dinv, Hh, b2, out, N);
    } else {
        // ---------------- fallback: round-1 atomic path ----------------
        size_t fo = 0;
        int* fdeg    = (int*)(base_p + fo);  fo = align_up(fo + (size_t)N * 4, 256);
        float* fdinv = (float*)(base_p + fo); fo = align_up(fo + (size_t)N * 4, 256);
        float* bufA  = (float*)(base_p + fo);
        hipMemsetAsync(fdeg, 0, (size_t)N * 4, stream);
        deg_kernel<<<gb_e, 256, 0, stream>>>(dstv, fdeg, nE);
        dinv_kernel<<<gb_n, 256, 0, stream>>>(fdeg, fdinv, N);
        int gb_i = (N * 16 + 255) / 256;
        int gb_e16 = (int)(((long long)nE * 16 + 255) / 256);
        gemm_xwt<<<gb_g, 256, 0, stream>>>(x, W1, bufA, N);
        init_out<<<gb_i, 256, 0, stream>>>(bufA, fdinv, b1, out, N);
        edge_scatter<<<gb_e16, 256, 0, stream>>>(src, dstv, fdinv, bufA, out, nE);
        gemm_xwt<<<gb_g, 256, 0, stream>>>(out, W2, bufA, N);
        init_out<<<gb_i, 256, 0, stream>>>(bufA, fdinv, b2, out, N);
        edge_scatter<<<gb_e16, 256, 0, stream>>>(src, dstv, fdinv, bufA, out, nE);
    }
}

// Round 6
// 298.307 us; speedup vs baseline: 5.4098x; 1.0231x over previous
//
#include <hip/hip_runtime.h>
#include <hip/hip_fp16.h>

// ---------------------------------------------------------------------------
// 2-layer GCN. Round 6: aggregate reworked to dual-edge half2 layout.
//  - lane l owns column pair (l&31) as float2; half-wave (l>>5) takes
//    alternate edges -> per edge-pair ONE full-width 256B gather instr
//    (vs two 128B) + one broadcast entry load; VALU/edge ~halved via
//    v_fma_mix on half2 operands. Halves merged with shfl_xor(32);
//    lanes 0-31 write coalesced float2 row.
//  - add_bases folded into scatter0 (bbase ready at launch). regroup stays
//    two kernels: dinv[src] is a cross-bucket dependency.
// Build (hist -> scans -> scatter0 -> regroup x2) amortized over 2 layers.
// ---------------------------------------------------------------------------

#define D 64
#define NPB 128          // nodes per bucket (dst >> 7)
#define MAXB 784         // >= ceil(100000/128) = 782
#define CHUNK 8192       // edges per partition chunk

// --- A1: per-chunk bucket histogram (LDS atomics only) ---------------------
__global__ __launch_bounds__(256) void hist_kernel(const int* __restrict__ dst,
                                                   int* __restrict__ counts,
                                                   int nE, int B) {
    __shared__ int hist[MAXB];
    int c = blockIdx.x;
    for (int b = threadIdx.x; b < B; b += 256) hist[b] = 0;
    __syncthreads();
    int e0 = c * CHUNK;
#pragma unroll
    for (int i = 0; i < CHUNK / 256; ++i) {
        int e = e0 + i * 256 + threadIdx.x;
        if (e < nE) atomicAdd(&hist[dst[e] >> 7], 1);
    }
    __syncthreads();
    for (int b = threadIdx.x; b < B; b += 256) counts[c * B + b] = hist[b];
}

// --- S1: per-bucket scan over chunks (one wave per bucket) -----------------
__global__ __launch_bounds__(256) void scan_chunks(const int* __restrict__ counts,
                                                   int* __restrict__ base,
                                                   int* __restrict__ bucketTotal,
                                                   int B, int C) {
    int b = blockIdx.x * 4 + (threadIdx.x >> 6);
    if (b >= B) return;
    int lane = threadIdx.x & 63;
    int running = 0;
    for (int c0 = 0; c0 < C; c0 += 64) {
        int c = c0 + lane;
        int v = (c < C) ? counts[c * B + b] : 0;
        int x = v;
#pragma unroll
        for (int s = 1; s < 64; s <<= 1) {
            int u = __shfl_up(x, s);
            if (lane >= s) x += u;
        }
        if (c < C) base[c * B + b] = running + x - v;   // exclusive within bucket
        running += __shfl(x, 63);
    }
    if (lane == 0) bucketTotal[b] = running;
}

// --- S2: block scan over bucket totals (B <= 1024) -------------------------
__global__ __launch_bounds__(1024) void scan_buckets(const int* __restrict__ bucketTotal,
                                                     int* __restrict__ bucketBase, int B) {
    __shared__ int sdata[1024];
    int t = threadIdx.x;
    int v = (t < B) ? bucketTotal[t] : 0;
    sdata[t] = v;
    __syncthreads();
    for (int s = 1; s < 1024; s <<= 1) {
        int u = (t >= s) ? sdata[t - s] : 0;
        __syncthreads();
        sdata[t] += u;
        __syncthreads();
    }
    if (t < B) bucketBase[t] = sdata[t] - v;       // exclusive
    if (t == B - 1) bucketBase[B] = sdata[t];      // total = nE
}

// --- A3: scatter 4B entries (src | dloc<<17) via LDS cursors ---------------
// bucketBase folded in here (was add_bases). Each (chunk,bucket) segment is
// written by exactly one workgroup -> near-1x HBM write traffic.
__global__ __launch_bounds__(256) void scatter0_kernel(const int* __restrict__ src,
                                                       const int* __restrict__ dst,
                                                       const int* __restrict__ base,
                                                       const int* __restrict__ bbase,
                                                       int* __restrict__ entries0,
                                                       int nE, int B) {
    __shared__ int cur[MAXB];
    int c = blockIdx.x;
    for (int b = threadIdx.x; b < B; b += 256) cur[b] = base[c * B + b] + bbase[b];
    __syncthreads();
    int e0 = c * CHUNK;
#pragma unroll
    for (int i = 0; i < CHUNK / 256; ++i) {
        int e = e0 + i * 256 + threadIdx.x;
        if (e < nE) {
            int s = src[e], d = dst[e];
            int pos = atomicAdd(&cur[d >> 7], 1);
            entries0[pos] = s | ((d & (NPB - 1)) << 17);
        }
    }
}

// --- A4: per-bucket node counts -> off / deg / dinv (no global atomics) ----
__global__ __launch_bounds__(256) void regroup_count(const int* __restrict__ entries0,
                                                     const int* __restrict__ bbase,
                                                     int* __restrict__ off,
                                                     int* __restrict__ deg,
                                                     float* __restrict__ dinv, int N) {
    __shared__ int cnt[NPB];
    __shared__ int scn[NPB];
    int b = blockIdx.x;
    int t = threadIdx.x;
    if (t < NPB) cnt[t] = 0;
    __syncthreads();
    int s0 = bbase[b], s1 = bbase[b + 1];
    for (int p = s0 + t; p < s1; p += 256)
        atomicAdd(&cnt[(entries0[p] >> 17) & (NPB - 1)], 1);
    __syncthreads();
    if (t < NPB) scn[t] = cnt[t];
    __syncthreads();
    for (int s = 1; s < NPB; s <<= 1) {
        int u = 0;
        if (t < NPB && t >= s) u = scn[t - s];
        __syncthreads();
        if (t < NPB) scn[t] += u;
        __syncthreads();
    }
    if (t < NPB) {
        int node = b * NPB + t;
        if (node < N) {
            int c = cnt[t];
            off[node]  = s0 + scn[t] - c;     // exclusive prefix
            deg[node]  = c;
            dinv[node] = rsqrtf((float)c + 1.0f);
        }
    }
}

// --- A5: node-sorted {src, norm} entries; writes within 16KB/bucket --------
__global__ __launch_bounds__(256) void regroup_scatter(const int* __restrict__ entries0,
                                                       const int* __restrict__ bbase,
                                                       const int* __restrict__ off,
                                                       const float* __restrict__ dinv,
                                                       int2* __restrict__ entries1, int N) {
    __shared__ int cur[NPB];
    int b = blockIdx.x;
    int t = threadIdx.x;
    if (t < NPB) {
        int node = b * NPB + t;
        cur[t] = (node < N) ? off[node] : 0;
    }
    __syncthreads();
    int s0 = bbase[b], s1 = bbase[b + 1];
    for (int p = s0 + t; p < s1; p += 256) {
        int e = entries0[p];
        int s = e & 0x1FFFF;
        int dloc = (e >> 17) & (NPB - 1);
        int pos = atomicAdd(&cur[dloc], 1);
        float nrm = dinv[s] * dinv[b * NPB + dloc];
        entries1[pos] = make_int2(s, __float_as_int(nrm));
    }
}

// --- aggregate2: one wave per node, dual-edge half2 layout -----------------
// lane l: column pair p2 = l&31 (cols 2*p2, 2*p2+1), half h = l>>5 takes
// edges p+h. Per edge-pair: 1 broadcast entry load + 1 full-width 256B
// gather. fp32 accumulate; halves merged via shfl_xor(32).
__global__ __launch_bounds__(256) void aggregate2(const int2* __restrict__ csr,
                                                  const int* __restrict__ off,
                                                  const int* __restrict__ deg,
                                                  const float* __restrict__ dinv,
                                                  const __half* __restrict__ H,
                                                  const float* __restrict__ bias,
                                                  float* __restrict__ out, int N) {
    int node = blockIdx.x * 4 + (threadIdx.x >> 6);
    if (node >= N) return;
    int lane = threadIdx.x & 63;
    int p2 = lane & 31;
    int h  = lane >> 5;
    const __half2* H2 = (const __half2*)H;
    float2 acc = make_float2(0.0f, 0.0f);
    int beg = off[node];
    int end = beg + deg[node];
    int p = beg;
    for (; p + 8 <= end; p += 8) {           // 8 edges: 4 gathers in flight
        int2 e0 = csr[p + 0 + h];
        int2 e1 = csr[p + 2 + h];
        int2 e2 = csr[p + 4 + h];
        int2 e3 = csr[p + 6 + h];
        __half2 g0 = H2[(size_t)e0.x * 32 + p2];
        __half2 g1 = H2[(size_t)e1.x * 32 + p2];
        __half2 g2 = H2[(size_t)e2.x * 32 + p2];
        __half2 g3 = H2[(size_t)e3.x * 32 + p2];
        float c0 = __int_as_float(e0.y), c1 = __int_as_float(e1.y);
        float c2 = __int_as_float(e2.y), c3 = __int_as_float(e3.y);
        float2 f0 = __half22float2(g0), f1 = __half22float2(g1);
        float2 f2 = __half22float2(g2), f3 = __half22float2(g3);
        acc.x += f0.x * c0; acc.y += f0.y * c0;
        acc.x += f1.x * c1; acc.y += f1.y * c1;
        acc.x += f2.x * c2; acc.y += f2.y * c2;
        acc.x += f3.x * c3; acc.y += f3.y * c3;
    }
    for (; p + 2 <= end; p += 2) {
        int2 e0 = csr[p + h];
        __half2 g0 = H2[(size_t)e0.x * 32 + p2];
        float c0 = __int_as_float(e0.y);
        float2 f0 = __half22float2(g0);
        acc.x += f0.x * c0; acc.y += f0.y * c0;
    }
    if (p < end && h == 0) {                 // odd tail: half 0 only
        int2 e0 = csr[p];
        __half2 g0 = H2[(size_t)e0.x * 32 + p2];
        float c0 = __int_as_float(e0.y);
        float2 f0 = __half22float2(g0);
        acc.x += f0.x * c0; acc.y += f0.y * c0;
    }
    acc.x += __shfl_xor(acc.x, 32);
    acc.y += __shfl_xor(acc.y, 32);
    if (h == 0) {
        float dd = dinv[node];
        float s = dd * dd;
        float2 hs = __half22float2(H2[(size_t)node * 32 + p2]);
        float2 bv = ((const float2*)bias)[p2];
        float2 o;
        o.x = acc.x + bv.x + hs.x * s;
        o.y = acc.y + bv.y + hs.y * s;
        ((float2*)(out + (size_t)node * D))[p2] = o;
    }
}

// --- H(fp16) = X(fp32) @ W^T : 64x64 block tile, 4x4 register tile ---------
__global__ __launch_bounds__(256) void gemm_xwt_h(const float* __restrict__ X,
                                                  const float* __restrict__ W,
                                                  __half* __restrict__ H, int N) {
    __shared__ float xt[64 * 68];
    __shared__ float wt[64 * 68];
    const int t = threadIdx.x;
    const int i0 = blockIdx.x * 64;
#pragma unroll
    for (int r = 0; r < 16; ++r) {
        int idx = r * 256 + t;
        int j = idx >> 6, k = idx & 63;
        wt[k * 68 + j] = W[idx];
    }
#pragma unroll
    for (int r = 0; r < 16; ++r) {
        int idx = r * 256 + t;
        int i = idx >> 6, k = idx & 63;
        float v = 0.0f;
        if (i0 + i < N) v = X[(size_t)(i0 + i) * D + k];
        xt[k * 68 + i] = v;
    }
    __syncthreads();
    const int tn = (t & 15) * 4;
    const int tc = (t >> 4) * 4;
    float acc[4][4] = {};
#pragma unroll 8
    for (int k = 0; k < 64; ++k) {
        const float4 xa = *(const float4*)(xt + k * 68 + tn);
        const float4 wb = *(const float4*)(wt + k * 68 + tc);
        acc[0][0] += xa.x * wb.x; acc[0][1] += xa.x * wb.y; acc[0][2] += xa.x * wb.z; acc[0][3] += xa.x * wb.w;
        acc[1][0] += xa.y * wb.x; acc[1][1] += xa.y * wb.y; acc[1][2] += xa.y * wb.z; acc[1][3] += xa.y * wb.w;
        acc[2][0] += xa.z * wb.x; acc[2][1] += xa.z * wb.y; acc[2][2] += xa.z * wb.z; acc[2][3] += xa.z * wb.w;
        acc[3][0] += xa.w * wb.x; acc[3][1] += xa.w * wb.y; acc[3][2] += xa.w * wb.z; acc[3][3] += xa.w * wb.w;
    }
#pragma unroll
    for (int a = 0; a < 4; ++a) {
        int i = i0 + tn + a;
        if (i < N) {
            union { __half2 h2[2]; uint2 u2; } pk;
            pk.h2[0].x = __float2half_rn(acc[a][0]);
            pk.h2[0].y = __float2half_rn(acc[a][1]);
            pk.h2[1].x = __float2half_rn(acc[a][2]);
            pk.h2[1].y = __float2half_rn(acc[a][3]);
            *(uint2*)(&H[(size_t)i * D + tc]) = pk.u2;
        }
    }
}

// --- fallback path (round-1 fp32 atomic) kernels ---------------------------
__global__ __launch_bounds__(256) void deg_kernel(const int* __restrict__ dst,
                                                  int* __restrict__ deg, int nE) {
    int e = blockIdx.x * 256 + threadIdx.x;
    if (e < nE) atomicAdd(&deg[dst[e]], 1);
}

__global__ __launch_bounds__(256) void dinv_kernel(const int* __restrict__ deg,
                                                   float* __restrict__ dinv, int N) {
    int i = blockIdx.x * 256 + threadIdx.x;
    if (i < N) dinv[i] = rsqrtf((float)deg[i] + 1.0f);
}

__global__ __launch_bounds__(256) void gemm_xwt(const float* __restrict__ X,
                                                const float* __restrict__ W,
                                                float* __restrict__ H, int N) {
    __shared__ float xt[64 * 68];
    __shared__ float wt[64 * 68];
    const int t = threadIdx.x;
    const int i0 = blockIdx.x * 64;
#pragma unroll
    for (int r = 0; r < 16; ++r) {
        int idx = r * 256 + t;
        int j = idx >> 6, k = idx & 63;
        wt[k * 68 + j] = W[idx];
    }
#pragma unroll
    for (int r = 0; r < 16; ++r) {
        int idx = r * 256 + t;
        int i = idx >> 6, k = idx & 63;
        float v = 0.0f;
        if (i0 + i < N) v = X[(size_t)(i0 + i) * D + k];
        xt[k * 68 + i] = v;
    }
    __syncthreads();
    const int tn = (t & 15) * 4;
    const int tc = (t >> 4) * 4;
    float acc[4][4] = {};
#pragma unroll 8
    for (int k = 0; k < 64; ++k) {
        const float4 xa = *(const float4*)(xt + k * 68 + tn);
        const float4 wb = *(const float4*)(wt + k * 68 + tc);
        acc[0][0] += xa.x * wb.x; acc[0][1] += xa.x * wb.y; acc[0][2] += xa.x * wb.z; acc[0][3] += xa.x * wb.w;
        acc[1][0] += xa.y * wb.x; acc[1][1] += xa.y * wb.y; acc[1][2] += xa.y * wb.z; acc[1][3] += xa.y * wb.w;
        acc[2][0] += xa.z * wb.x; acc[2][1] += xa.z * wb.y; acc[2][2] += xa.z * wb.z; acc[2][3] += xa.z * wb.w;
        acc[3][0] += xa.w * wb.x; acc[3][1] += xa.w * wb.y; acc[3][2] += xa.w * wb.z; acc[3][3] += xa.w * wb.w;
    }
#pragma unroll
    for (int a = 0; a < 4; ++a) {
        int i = i0 + tn + a;
        if (i < N) {
            float4 o = make_float4(acc[a][0], acc[a][1], acc[a][2], acc[a][3]);
            *(float4*)(H + (size_t)i * D + tc) = o;
        }
    }
}

__global__ __launch_bounds__(256) void init_out(const float* __restrict__ H,
                                                const float* __restrict__ dinv,
                                                const float* __restrict__ b,
                                                float* __restrict__ out, int N) {
    int idx4 = blockIdx.x * 256 + threadIdx.x;
    if (idx4 >= N * 16) return;
    int i = idx4 >> 4;
    int jc = idx4 & 15;
    float di = dinv[i];
    float s = di * di;
    float4 h4 = ((const float4*)H)[idx4];
    float4 b4 = ((const float4*)b)[jc];
    ((float4*)out)[idx4] = make_float4(b4.x + h4.x * s, b4.y + h4.y * s,
                                       b4.z + h4.z * s, b4.w + h4.w * s);
}

__global__ __launch_bounds__(256) void edge_scatter(const int* __restrict__ src,
                                                    const int* __restrict__ dst,
                                                    const float* __restrict__ dinv,
                                                    const float* __restrict__ H,
                                                    float* __restrict__ out, int nE) {
    int tid = blockIdx.x * 256 + threadIdx.x;
    int e = tid >> 4;
    if (e >= nE) return;
    int l = tid & 15;
    int s = src[e];
    int d = dst[e];
    float c = dinv[s] * dinv[d];
    float4 v = ((const float4*)H)[s * 16 + l];
    float* o = out + (size_t)d * D + l * 4;
    unsafeAtomicAdd(o + 0, v.x * c);
    unsafeAtomicAdd(o + 1, v.y * c);
    unsafeAtomicAdd(o + 2, v.z * c);
    unsafeAtomicAdd(o + 3, v.w * c);
}

static inline size_t align_up(size_t v, size_t a) { return (v + a - 1) & ~(a - 1); }

extern "C" void kernel_launch(void* const* d_in, const int* in_sizes, int n_in,
                              void* d_out, int out_size, void* d_ws, size_t ws_size,
                              hipStream_t stream) {
    const float* x  = (const float*)d_in[0];
    const int*   ei = (const int*)d_in[1];
    const float* W1 = (const float*)d_in[2];
    const float* b1 = (const float*)d_in[3];
    const float* W2 = (const float*)d_in[4];
    const float* b2 = (const float*)d_in[5];
    float* out = (float*)d_out;

    const int N  = in_sizes[0] / D;   // 100000
    const int nE = in_sizes[1] / 2;   // 1600000
    const int* src = ei;
    const int* dstv = ei + nE;

    const int B = (N + NPB - 1) / NPB;      // 782
    const int C = (nE + CHUNK - 1) / CHUNK; // 196

    // --- workspace layout (bump allocator, 256B aligned) ---
    char* base_p = (char*)d_ws;
    size_t o = 0;
    int* counts = (int*)(base_p + o);  o = align_up(o + (size_t)C * B * 4, 256);
    int* cbase  = (int*)(base_p + o);  o = align_up(o + (size_t)C * B * 4, 256);
    int* btot   = (int*)(base_p + o);  o = align_up(o + (size_t)B * 4, 256);
    int* bbase  = (int*)(base_p + o);  o = align_up(o + (size_t)(B + 1) * 4, 256);
    int* off    = (int*)(base_p + o);  o = align_up(o + (size_t)N * 4, 256);
    int* deg    = (int*)(base_p + o);  o = align_up(o + (size_t)N * 4, 256);
    float* dinv = (float*)(base_p + o); o = align_up(o + (size_t)N * 4, 256);
    int2* entries1 = (int2*)(base_p + o); o = align_up(o + (size_t)nE * 8, 256);
    // region2: entries0 (nE*4) while building; Hh (N*D*2) afterwards (aliased)
    size_t r2 = (size_t)nE * 4 > (size_t)N * D * 2 ? (size_t)nE * 4 : (size_t)N * D * 2;
    int* entries0 = (int*)(base_p + o);
    __half* Hh    = (__half*)(base_p + o);
    o = align_up(o + r2, 256);
    size_t need = o;   // ~28 MB

    int gb_n = (N + 255) / 256;
    int gb_g = (N + 63) / 64;
    int gb_e = (nE + 255) / 256;

    if (ws_size >= need && B <= MAXB && B <= 1024) {
        // ---- partition build (once, reused both layers) ----
        hist_kernel<<<C, 256, 0, stream>>>(dstv, counts, nE, B);
        scan_chunks<<<(B + 3) / 4, 256, 0, stream>>>(counts, cbase, btot, B, C);
        scan_buckets<<<1, 1024, 0, stream>>>(btot, bbase, B);
        scatter0_kernel<<<C, 256, 0, stream>>>(src, dstv, cbase, bbase, entries0, nE, B);
        regroup_count<<<B, 256, 0, stream>>>(entries0, bbase, off, deg, dinv, N);
        regroup_scatter<<<B, 256, 0, stream>>>(entries0, bbase, off, dinv, entries1, N);
        // (entries0 dead from here; its memory becomes Hh)

        int gb_a = (N + 3) / 4;
        // layer 1
        gemm_xwt_h<<<gb_g, 256, 0, stream>>>(x, W1, Hh, N);
        aggregate2<<<gb_a, 256, 0, stream>>>(entries1, off, deg, dinv, Hh, b1, out, N);
        // layer 2 (agg1 lives in d_out, fp32)
        gemm_xwt_h<<<gb_g, 256, 0, stream>>>(out, W2, Hh, N);
        aggregate2<<<gb_a, 256, 0, stream>>>(entries1, off, deg, dinv, Hh, b2, out, N);
    } else {
        // ---------------- fallback: round-1 atomic path ----------------
        size_t fo = 0;
        int* fdeg    = (int*)(base_p + fo);  fo = align_up(fo + (size_t)N * 4, 256);
        float* fdinv = (float*)(base_p + fo); fo = align_up(fo + (size_t)N * 4, 256);
        float* bufA  = (float*)(base_p + fo);
        hipMemsetAsync(fdeg, 0, (size_t)N * 4, stream);
        deg_kernel<<<gb_e, 256, 0, stream>>>(dstv, fdeg, nE);
        dinv_kernel<<<gb_n, 256, 0, stream>>>(fdeg, fdinv, N);
        int gb_i = (N * 16 + 255) / 256;
        int gb_e16 = (int)(((long long)nE * 16 + 255) / 256);
        gemm_xwt<<<gb_g, 256, 0, stream>>>(x, W1, bufA, N);
        init_out<<<gb_i, 256, 0, stream>>>(bufA, fdinv, b1, out, N);
        edge_scatter<<<gb_e16, 256, 0, stream>>>(src, dstv, fdinv, bufA, out, nE);
        gemm_xwt<<<gb_g, 256, 0, stream>>>(out, W2, bufA, N);
        init_out<<<gb_i, 256, 0, stream>>>(bufA, fdinv, b2, out, N);
        edge_scatter<<<gb_e16, 256, 0, stream>>>(src, dstv, fdinv, bufA, out, nE);
    }
}